// Round 9
// baseline (256.130 us; speedup 1.0000x reference)
//
#include <hip/hip_runtime.h>
#include <stdint.h>

typedef __attribute__((ext_vector_type(8))) short short8;
typedef __attribute__((ext_vector_type(4))) float f32x4;

__device__ __forceinline__ unsigned short f2bf(float f) {
  unsigned u = __float_as_uint(f);
  u += 0x7FFF + ((u >> 16) & 1);
  return (unsigned short)(u >> 16);
}
__device__ __forceinline__ float bf2f(unsigned short h) {
  return __uint_as_float(((unsigned)h) << 16);
}

// Packed fragment layout (k-major) for mfma_f32_16x16x32_bf16 operands:
// frag tile (rt, kc): short off = (kc*NRT + rt)*512 + lane*8,
// lane = (row&15) + 16*((k&31)>>3), elem = k&7. 1 frag = wave-contiguous 1KB.

// ---------------- merged prep: pack x + low (blocks 0..787), pack weights, zero V pads ----------------
__global__ __launch_bounds__(256) void k_prep2(const float* __restrict__ x,
                                               const float* __restrict__ lora_a,
                                               const float* __restrict__ qkv_w,
                                               const float* __restrict__ out_w,
                                               unsigned short* __restrict__ Apk,
                                               float* __restrict__ low,
                                               unsigned short* __restrict__ Wq,
                                               unsigned short* __restrict__ Wo,
                                               unsigned short* __restrict__ vt) {
  __shared__ unsigned short xs[16 * 776];
  __shared__ float As[8 * 768];
  const int bid = blockIdx.x;
  const int t = threadIdx.x;
  if (bid < 788) {
    const int mt = bid;
    const float4* x4 = (const float4*)(x + (size_t)mt * 16 * 768);
#pragma unroll
    for (int i = 0; i < 12; ++i) {
      float4 v = x4[i * 256 + t];
      int e0 = (i * 256 + t) * 4;
      int row = e0 / 768, col = e0 - row * 768;
      unsigned short* d = &xs[row * 776 + col];
      d[0] = f2bf(v.x); d[1] = f2bf(v.y); d[2] = f2bf(v.z); d[3] = f2bf(v.w);
    }
    for (int i = t; i < 1536; i += 256) ((float4*)As)[i] = ((const float4*)lora_a)[i];
    __syncthreads();
    const int w = t >> 6, l = t & 63;
    float acc[4][8];
#pragma unroll
    for (int r = 0; r < 4; ++r)
#pragma unroll
      for (int k = 0; k < 8; ++k) acc[r][k] = 0.f;
    for (int j = 0; j < 12; ++j) {
      int d = j * 64 + l;
#pragma unroll
      for (int r = 0; r < 4; ++r) {
        float xv = bf2f(xs[(w * 4 + r) * 776 + d]);
#pragma unroll
        for (int k = 0; k < 8; ++k) acc[r][k] += xv * As[k * 768 + d];
      }
    }
#pragma unroll
    for (int r = 0; r < 4; ++r)
#pragma unroll
      for (int k = 0; k < 8; ++k) {
        float a = acc[r][k];
        for (int dd = 1; dd < 64; dd <<= 1) a += __shfl_xor(a, dd);
        if (l == 0) low[((size_t)mt * 16 + w * 4 + r) * 8 + k] = 2.0f * a;
      }
    const int lr = l & 15, lg = l >> 4;
#pragma unroll
    for (int kk = 0; kk < 6; ++kk) {
      int kc = w * 6 + kk;
      short8 v = *(const short8*)(&xs[lr * 776 + kc * 32 + lg * 8]);
      *(short8*)(Apk + (size_t)(kc * 788 + mt) * 512 + l * 8) = v;
    }
  } else if (bid < 1940) {
    const bool isq = bid < 1652;
    const float* W = isq ? qkv_w : out_w;
    unsigned short* dst = isq ? Wq : Wo;
    const int NRT = isq ? 144 : 48;
    const int base = isq ? 788 : 1652;
    int wv = ((bid - base) * 256 + t) >> 6;
    int l = t & 63;
    int rt = wv / 24, kc = wv - rt * 24;
    int lr = l & 15, lg = l >> 4;
    const float* src = W + (size_t)(rt * 16 + lr) * 768 + kc * 32 + lg * 8;
    float4 a = *(const float4*)src;
    float4 b = *(const float4*)(src + 4);
    short8 o;
    o[0] = f2bf(a.x); o[1] = f2bf(a.y); o[2] = f2bf(a.z); o[3] = f2bf(a.w);
    o[4] = f2bf(b.x); o[5] = f2bf(b.y); o[6] = f2bf(b.z); o[7] = f2bf(b.w);
    *(short8*)(dst + (size_t)(kc * NRT + rt) * 512 + l * 8) = o;
  } else {
    int r = (bid - 1940) * 256 + t;  // [0, 49152)
    unsigned short* d = vt + (size_t)r * 224 + 197;
#pragma unroll
    for (int c = 0; c < 27; ++c) d[c] = 0;
  }
}

// ---------------- rank-8 LoRA low from PACKED (k-major) bf16 input ----------------
__global__ __launch_bounds__(256) void k_low_pk(const unsigned short* __restrict__ Apk,
                                                const float* __restrict__ lora_a,
                                                float* __restrict__ low, int M) {
  __shared__ float As[8 * 768];
  for (int i = threadIdx.x; i < 1536; i += 256) ((float4*)As)[i] = ((const float4*)lora_a)[i];
  __syncthreads();
  int w = threadIdx.x >> 6, l = threadIdx.x & 63;
  int m = blockIdx.x * 4 + w;
  if (m >= M) return;
  const int mt = m >> 4, mr = m & 15;
  const int kcb = l >> 5, lgp = (l & 31) >> 3, e = l & 7;
  float acc[8] = {0, 0, 0, 0, 0, 0, 0, 0};
  for (int j = 0; j < 12; ++j) {
    int d = j * 64 + l;
    float xv = bf2f(Apk[((size_t)((j * 2 + kcb) * 788 + mt) * 64 + mr + 16 * lgp) * 8 + e]);
#pragma unroll
    for (int r = 0; r < 8; ++r) acc[r] += xv * As[r * 768 + d];
  }
#pragma unroll
  for (int r = 0; r < 8; ++r) {
    for (int dd = 1; dd < 64; dd <<= 1) acc[r] += __shfl_xor(acc[r], dd);
    if (l == 0) low[(size_t)m * 8 + r] = 2.0f * acc[r];
  }
}

// ---------------- 256x256 LDS GEMM, BK=32, 4-slot / 3-tile-deep pipeline ----------------
// Packed operands -> linear LDS (conflict-free), 1 barrier + 1 counted vmcnt per K-tile.
// 512 thr = 8 waves (2m x 4n), wave tile 128x64. 24 K-tiles (K=768).
// MODE 0: qkv (NT=9, NRTB=144) scatter epilogue. MODE 1: out (NT=3, NRTB=48) f32 out.
template <int MODE, int NT, int NRTB>
__global__ __launch_bounds__(512, 2) void k_g8(
    const unsigned short* __restrict__ Apk, const unsigned short* __restrict__ Bpk,
    const float* __restrict__ bias, const float* __restrict__ low,
    const float* __restrict__ lorab, unsigned short* __restrict__ Qg,
    unsigned short* __restrict__ Kg, unsigned short* __restrict__ Vtg,
    float* __restrict__ outp, int M) {
  __shared__ __align__(16) char lds[131072];  // 4 slots x (A 16KB + B 16KB)
  const int tid = threadIdx.x;
  const int w = tid >> 6, l = tid & 63;
  const int lr = l & 15, lg = l >> 4;
  const int wm = w >> 2, wn = w & 3;
  // bijective XCD swizzle (m204); nt fastest so same-mg blocks share A panel in L2
  const int nwg = gridDim.x;
  const int orig = blockIdx.x;
  const int qq = nwg >> 3, rr = nwg & 7, xcd = orig & 7;
  const int wgid = (xcd < rr ? xcd * (qq + 1) : rr * (qq + 1) + (xcd - rr) * qq) + (orig >> 3);
  const int mg = wgid / NT, nt = wgid - mg * NT;
  const int m0 = mg * 256, n0 = nt * 256;

  auto* lds3 = (__attribute__((address_space(3))) char*)lds;
  const char* ldsc = (const char*)lds;

  f32x4 acc[8][4];
#pragma unroll
  for (int i = 0; i < 8; ++i)
#pragma unroll
    for (int j = 0; j < 4; ++j) acc[i][j] = (f32x4){0.f, 0.f, 0.f, 0.f};

  // stage K-tile t (plane kc=t): A 16KB + B 16KB, 4 global_load_lds per wave
  auto STAGE_A = [&](int t) {
    const int slot = t & 3;
    const unsigned short* g = Apk + ((size_t)t * 788 + mg * 16) * 512 + w * 512 + l * 8;
    __builtin_amdgcn_global_load_lds((const __attribute__((address_space(1))) void*)g,
                                     (__attribute__((address_space(3))) void*)(lds3 + slot * 32768 + w * 1024),
                                     16, 0, 0);
    __builtin_amdgcn_global_load_lds((const __attribute__((address_space(1))) void*)(g + 4096),
                                     (__attribute__((address_space(3))) void*)(lds3 + slot * 32768 + 8192 + w * 1024),
                                     16, 0, 0);
  };
  auto STAGE_B = [&](int t) {
    const int slot = t & 3;
    const unsigned short* g = Bpk + ((size_t)t * NRTB + nt * 16) * 512 + w * 512 + l * 8;
    __builtin_amdgcn_global_load_lds((const __attribute__((address_space(1))) void*)g,
                                     (__attribute__((address_space(3))) void*)(lds3 + slot * 32768 + 16384 + w * 1024),
                                     16, 0, 0);
    __builtin_amdgcn_global_load_lds((const __attribute__((address_space(1))) void*)(g + 4096),
                                     (__attribute__((address_space(3))) void*)(lds3 + slot * 32768 + 24576 + w * 1024),
                                     16, 0, 0);
  };

  // prologue: stage tiles 0,1,2 (12 instr/wave); wait tile0 (tiles 1,2 = 8 in flight)
  STAGE_A(0); STAGE_B(0);
  STAGE_A(1); STAGE_B(1);
  STAGE_A(2); STAGE_B(2);
  asm volatile("s_waitcnt vmcnt(8)" ::: "memory");
  __builtin_amdgcn_sched_barrier(0);
  __builtin_amdgcn_s_barrier();

#pragma unroll
  for (int t = 0; t < 24; ++t) {
    const int slot = t & 3;
    const char* sb = ldsc + slot * 32768;
    short8 bfr[4], af[8];
#pragma unroll
    for (int nf = 0; nf < 4; ++nf)
      bfr[nf] = *(const short8*)(sb + 16384 + (wn * 4 + nf) * 1024 + l * 16);
#pragma unroll
    for (int mf = 0; mf < 8; ++mf)
      af[mf] = *(const short8*)(sb + (wm * 8 + mf) * 1024 + l * 16);
    if (t + 3 < 24) { STAGE_A(t + 3); STAGE_B(t + 3); }
    __builtin_amdgcn_s_setprio(1);
#pragma unroll
    for (int mf = 0; mf < 8; ++mf)
#pragma unroll
      for (int nf = 0; nf < 4; ++nf)
        acc[mf][nf] = __builtin_amdgcn_mfma_f32_16x16x32_bf16(af[mf], bfr[nf], acc[mf][nf], 0, 0, 0);
    __builtin_amdgcn_s_setprio(0);
    // boundary: next tile's 4 chunks must have landed; keep deeper tiles in flight
    if (t < 20) {
      asm volatile("s_waitcnt vmcnt(8)" ::: "memory");
      __builtin_amdgcn_sched_barrier(0);
      __builtin_amdgcn_s_barrier();
    } else if (t == 20) {
      asm volatile("s_waitcnt vmcnt(8)" ::: "memory");
      __builtin_amdgcn_sched_barrier(0);
      __builtin_amdgcn_s_barrier();
    } else if (t == 21) {
      asm volatile("s_waitcnt vmcnt(4)" ::: "memory");
      __builtin_amdgcn_sched_barrier(0);
      __builtin_amdgcn_s_barrier();
    } else if (t == 22) {
      asm volatile("s_waitcnt vmcnt(0)" ::: "memory");
      __builtin_amdgcn_sched_barrier(0);
      __builtin_amdgcn_s_barrier();
    }
  }

  // epilogue: bias + rank-8 LoRA; MODE 0 scatter to Q/K/Vt bf16, MODE 1 f32 out
  float bo[4];
  float4 lb0[4], lb1[4];
  int which[4], hh[4], hd[4], ocol[4];
#pragma unroll
  for (int nf = 0; nf < 4; ++nf) {
    int o = n0 + wn * 64 + nf * 16 + lr;
    ocol[nf] = o;
    bo[nf] = bias[o];
    const float4* lb4 = (const float4*)(lorab + (size_t)o * 8);
    lb0[nf] = lb4[0];
    lb1[nf] = lb4[1];
    if (MODE == 0) {
      which[nf] = o / 768;
      int within = o - which[nf] * 768;
      hh[nf] = within >> 6;
      hd[nf] = within & 63;
    }
  }
#pragma unroll
  for (int mf = 0; mf < 8; ++mf) {
#pragma unroll
    for (int v = 0; v < 4; ++v) {
      int m = m0 + wm * 128 + mf * 16 + lg * 4 + v;
      if (m < M) {
        const float4* lp4 = (const float4*)(low + (size_t)m * 8);
        float4 l0 = lp4[0], l1 = lp4[1];
        int b = m / 197;
        int n = m - b * 197;
#pragma unroll
        for (int nf = 0; nf < 4; ++nf) {
          float val = acc[mf][nf][v] + bo[nf];
          val += l0.x * lb0[nf].x + l0.y * lb0[nf].y + l0.z * lb0[nf].z + l0.w * lb0[nf].w;
          val += l1.x * lb1[nf].x + l1.y * lb1[nf].y + l1.z * lb1[nf].z + l1.w * lb1[nf].w;
          if (MODE == 0) {
            int bh = b * 12 + hh[nf];
            unsigned short hv = f2bf(val);
            if (which[nf] == 0)      Qg[(bh * 224 + n) * 64 + hd[nf]] = hv;
            else if (which[nf] == 1) Kg[(bh * 224 + n) * 64 + hd[nf]] = hv;
            else                     Vtg[(bh * 64 + hd[nf]) * 224 + n] = hv;
          } else {
            outp[(size_t)m * 768 + ocol[nf]] = val;
          }
        }
      }
    }
  }
}

// ---------------- attention: one block per (b,h); writes PACKED (k-major) aout ----------------
__global__ __launch_bounds__(256) void k_attn(const unsigned short* __restrict__ Qg,
                                              const unsigned short* __restrict__ Kg,
                                              const unsigned short* __restrict__ Vtg,
                                              unsigned short* __restrict__ Apk) {
  __shared__ __align__(16) unsigned short Ps[4][16 * 224];
  const int bh = blockIdx.x;
  const int b = bh / 12, h = bh - b * 12;
  const unsigned short* Qb = Qg + (size_t)bh * (224 * 64);
  const unsigned short* Kb = Kg + (size_t)bh * (224 * 64);
  const unsigned short* Vb = Vtg + (size_t)bh * (64 * 224);
  const int w = threadIdx.x >> 6, l = threadIdx.x & 63;
  const int lr = l & 15, lg = l >> 4;
  for (int t = w; t < 13; t += 4) {
    const int q0 = t * 16;
    short8 aq0 = *(const short8*)(Qb + (q0 + lr) * 64 + lg * 8);
    short8 aq1 = *(const short8*)(Qb + (q0 + lr) * 64 + 32 + lg * 8);
    f32x4 s[14];
#pragma unroll
    for (int jt = 0; jt < 14; ++jt) {
      f32x4 a = (f32x4){0.f, 0.f, 0.f, 0.f};
      short8 bk0 = *(const short8*)(Kb + (jt * 16 + lr) * 64 + lg * 8);
      short8 bk1 = *(const short8*)(Kb + (jt * 16 + lr) * 64 + 32 + lg * 8);
      a = __builtin_amdgcn_mfma_f32_16x16x32_bf16(aq0, bk0, a, 0, 0, 0);
      a = __builtin_amdgcn_mfma_f32_16x16x32_bf16(aq1, bk1, a, 0, 0, 0);
      s[jt] = a;
    }
    float mx[4] = {-3.0e38f, -3.0e38f, -3.0e38f, -3.0e38f};
#pragma unroll
    for (int jt = 0; jt < 14; ++jt) {
      bool valid = (jt * 16 + lr) < 197;
#pragma unroll
      for (int v = 0; v < 4; ++v) {
        float sv = valid ? s[jt][v] : -1.0e30f;
        s[jt][v] = sv;
        mx[v] = fmaxf(mx[v], sv);
      }
    }
#pragma unroll
    for (int v = 0; v < 4; ++v) {
      mx[v] = fmaxf(mx[v], __shfl_xor(mx[v], 1));
      mx[v] = fmaxf(mx[v], __shfl_xor(mx[v], 2));
      mx[v] = fmaxf(mx[v], __shfl_xor(mx[v], 4));
      mx[v] = fmaxf(mx[v], __shfl_xor(mx[v], 8));
    }
    float sum[4] = {0.f, 0.f, 0.f, 0.f};
    const float cc = 0.125f * 1.44269504088896341f;
#pragma unroll
    for (int jt = 0; jt < 14; ++jt)
#pragma unroll
      for (int v = 0; v < 4; ++v) {
        float pv = exp2f((s[jt][v] - mx[v]) * cc);
        s[jt][v] = pv;
        sum[v] += pv;
      }
#pragma unroll
    for (int v = 0; v < 4; ++v) {
      sum[v] += __shfl_xor(sum[v], 1);
      sum[v] += __shfl_xor(sum[v], 2);
      sum[v] += __shfl_xor(sum[v], 4);
      sum[v] += __shfl_xor(sum[v], 8);
    }
    float inv[4];
#pragma unroll
    for (int v = 0; v < 4; ++v) inv[v] = 1.0f / sum[v];
    unsigned short* pw = &Ps[w][0];
#pragma unroll
    for (int jt = 0; jt < 14; ++jt)
#pragma unroll
      for (int v = 0; v < 4; ++v)
        pw[(lg * 4 + v) * 224 + jt * 16 + lr] = f2bf(s[jt][v] * inv[v]);
    f32x4 oacc[4];
#pragma unroll
    for (int jo = 0; jo < 4; ++jo) oacc[jo] = (f32x4){0.f, 0.f, 0.f, 0.f};
#pragma unroll
    for (int kk = 0; kk < 7; ++kk) {
      short8 pa = *(const short8*)(pw + lr * 224 + kk * 32 + lg * 8);
#pragma unroll
      for (int jo = 0; jo < 4; ++jo) {
        short8 bv = *(const short8*)(Vb + (jo * 16 + lr) * 224 + kk * 32 + lg * 8);
        oacc[jo] = __builtin_amdgcn_mfma_f32_16x16x32_bf16(pa, bv, oacc[jo], 0, 0, 0);
      }
    }
#pragma unroll
    for (int jo = 0; jo < 4; ++jo) {
      const int kc = h * 2 + (jo >> 1);
      const int lgp = (jo & 1) * 2 + (lr >> 3);
      const int e = lr & 7;
#pragma unroll
      for (int v = 0; v < 4; ++v) {
        int n = q0 + lg * 4 + v;
        if (n < 197) {
          int m = b * 197 + n;
          Apk[((size_t)(kc * 788 + (m >> 4)) * 64 + (m & 15) + 16 * lgp) * 8 + e] = f2bf(oacc[jo][v]);
        }
      }
    }
  }
}

extern "C" void kernel_launch(void* const* d_in, const int* in_sizes, int n_in,
                              void* d_out, int out_size, void* d_ws, size_t ws_size,
                              hipStream_t stream) {
  const float* x      = (const float*)d_in[0];
  const float* qkv_w  = (const float*)d_in[1];
  const float* qkv_b  = (const float*)d_in[2];
  const float* qkv_la = (const float*)d_in[3];
  const float* qkv_lb = (const float*)d_in[4];
  const float* out_w  = (const float*)d_in[5];
  const float* out_b  = (const float*)d_in[6];
  const float* out_la = (const float*)d_in[7];
  const float* out_lb = (const float*)d_in[8];
  float* out = (float*)d_out;

  const int M = 64 * 197;  // 12608 = 788*16 = 197*64
  char* p = (char*)d_ws;
  auto carve = [&](size_t bytes) {
    char* r = p;
    p += (bytes + 255) & ~(size_t)255;
    return r;
  };
  // +32KB pad: mg=49 staging reads rt 784..799 (past 788) — keep in-bounds
  unsigned short* Apk  = (unsigned short*)carve((size_t)788 * 24 * 512 * 2 + 32768);
  unsigned short* Wqpk = (unsigned short*)carve((size_t)144 * 24 * 512 * 2);
  unsigned short* Wopk = (unsigned short*)carve((size_t)48 * 24 * 512 * 2);
  float* lowq          = (float*)carve((size_t)M * 8 * 4);
  float* lowo          = (float*)carve((size_t)M * 8 * 4);
  unsigned short* Qg   = (unsigned short*)carve((size_t)768 * 224 * 64 * 2);
  unsigned short* Kg   = (unsigned short*)carve((size_t)768 * 224 * 64 * 2);
  unsigned short* Vtg  = (unsigned short*)carve((size_t)768 * 64 * 224 * 2);

  // merged prep: 788 (pack x + low) + 864 (pack qkv_w) + 288 (pack out_w) + 192 (V pads)
  k_prep2<<<2132, 256, 0, stream>>>(x, qkv_la, qkv_w, out_w, Apk, lowq, Wqpk, Wopk, Vtg);
  // qkv: 50 mg x 9 nt = 450 blocks of 512 thr
  k_g8<0, 9, 144><<<450, 512, 0, stream>>>(Apk, Wqpk, qkv_b, lowq, qkv_lb, Qg, Kg, Vtg, nullptr, M);
  k_attn<<<768, 256, 0, stream>>>(Qg, Kg, Vtg, Apk);  // Apk now holds packed attn-out
  k_low_pk<<<(M + 3) / 4, 256, 0, stream>>>(Apk, out_la, lowo, M);
  // out: 50 mg x 3 nt = 150 blocks
  k_g8<1, 3, 48><<<150, 512, 0, stream>>>(Apk, Wopk, out_b, lowo, out_lb, nullptr, nullptr, nullptr, out, M);
}